// Round 1
// baseline (589.989 us; speedup 1.0000x reference)
//
#include <hip/hip_runtime.h>

typedef __attribute__((ext_vector_type(8))) short bf16x8;
typedef __attribute__((ext_vector_type(4))) float f32x4;
typedef __attribute__((ext_vector_type(4))) unsigned short u16x4;

#define GPTR(p) (const __attribute__((address_space(1))) void*)(p)
#define LPTR(p) (__attribute__((address_space(3))) void*)(p)

static __device__ __forceinline__ unsigned short f2bf(float f) {
  union { float f; unsigned int u; } x; x.f = f;
  unsigned int u = x.u;
  unsigned int r = (u + 0x7fffu + ((u >> 16) & 1u)) >> 16;
  return (unsigned short)r;
}
static __device__ __forceinline__ float bf2f(unsigned short h) {
  union { unsigned int u; float f; } x; x.u = ((unsigned int)h) << 16;
  return x.f;
}
static __device__ __forceinline__ f32x4 f32x4_zero() {
  f32x4 z = {0.f, 0.f, 0.f, 0.f}; return z;
}

// ---------------------------------------------------------------- RoPE table
// costab/sintab: [2048][32] fp32, angle = s * 10000^(-d/32)
__global__ void rope_table_kernel(float* __restrict__ costab, float* __restrict__ sintab) {
  int i = blockIdx.x * blockDim.x + threadIdx.x;   // 65536 total
  int s = i >> 5, d = i & 31;
  // 10000^(-d/32) = 2^(-d * log2(10000)/32)
  float invf = exp2f(-(float)d * (13.287712379549449f / 32.0f));
  float a = (float)s * invf;
  costab[i] = cosf(a);
  sintab[i] = sinf(a);
}

// ---------------------------------------------------------------- f32 -> bf16
__global__ void f32_to_bf16(const float* __restrict__ src, unsigned short* __restrict__ dst, int n4) {
  int stride = gridDim.x * blockDim.x;
  for (int i = blockIdx.x * blockDim.x + threadIdx.x; i < n4; i += stride) {
    float4 v = ((const float4*)src)[i];
    u16x4 o;
    o.x = f2bf(v.x); o.y = f2bf(v.y); o.z = f2bf(v.z); o.w = f2bf(v.w);
    *(u16x4*)(dst + (size_t)i * 4) = o;
  }
}

// ---------------------------------------------------------------- GEMM C = A @ B^T
// A: M x K bf16 row-major. B: N x K bf16 row-major. 128x128 tile, BK=32,
// 4 waves (2x2), each wave 64x64 = 4x4 fragments of 16x16x32 MFMA (m97 structure).
template<int OUT_BF16>
__global__ __launch_bounds__(256) void gemm_bt(const unsigned short* __restrict__ A,
                                               const unsigned short* __restrict__ B,
                                               void* __restrict__ Cv, int N, int K) {
  __shared__ __align__(16) unsigned short lsA[128 * 32];
  __shared__ __align__(16) unsigned short lsB[128 * 32];
  const int tid = threadIdx.x;
  const int wave = tid >> 6, lane = tid & 63;
  const int fq = lane >> 4, fr = lane & 15;
  const int wr = wave >> 1, wc = wave & 1;
  const int m0 = blockIdx.y * 128, n0 = blockIdx.x * 128;

  // staging: thread t covers 16B at tile byte offset c*4096 + t*16
  //   row = c*64 + t/4 ; col8 = (t%4)*8
  const unsigned short* ga0 = A + (size_t)(m0 + (tid >> 2)) * K + ((tid & 3) << 3);
  const unsigned short* ga1 = ga0 + (size_t)64 * K;
  const unsigned short* gb0 = B + (size_t)(n0 + (tid >> 2)) * K + ((tid & 3) << 3);
  const unsigned short* gb1 = gb0 + (size_t)64 * K;
  unsigned short* lA0 = lsA + wave * 512;        // bytes: wave*1024
  unsigned short* lA1 = lsA + 2048 + wave * 512; // bytes: 4096 + wave*1024
  unsigned short* lB0 = lsB + wave * 512;
  unsigned short* lB1 = lsB + 2048 + wave * 512;

  f32x4 acc[4][4];
#pragma unroll
  for (int i = 0; i < 4; ++i)
#pragma unroll
    for (int j = 0; j < 4; ++j) acc[i][j] = f32x4_zero();

  for (int k0 = 0; k0 < K; k0 += 32) {
    __syncthreads();
    __builtin_amdgcn_global_load_lds(GPTR(ga0 + k0), LPTR(lA0), 16, 0, 0);
    __builtin_amdgcn_global_load_lds(GPTR(ga1 + k0), LPTR(lA1), 16, 0, 0);
    __builtin_amdgcn_global_load_lds(GPTR(gb0 + k0), LPTR(lB0), 16, 0, 0);
    __builtin_amdgcn_global_load_lds(GPTR(gb1 + k0), LPTR(lB1), 16, 0, 0);
    __syncthreads();
    bf16x8 af[4], bfr[4];
#pragma unroll
    for (int f = 0; f < 4; ++f) {
      af[f]  = *(const bf16x8*)(lsA + (wr * 64 + f * 16 + fr) * 32 + fq * 8);
      bfr[f] = *(const bf16x8*)(lsB + (wc * 64 + f * 16 + fr) * 32 + fq * 8);
    }
#pragma unroll
    for (int i = 0; i < 4; ++i)
#pragma unroll
      for (int j = 0; j < 4; ++j)
        acc[i][j] = __builtin_amdgcn_mfma_f32_16x16x32_bf16(af[i], bfr[j], acc[i][j], 0, 0, 0);
  }

#pragma unroll
  for (int i = 0; i < 4; ++i) {
    const int row = m0 + wr * 64 + i * 16 + fq * 4;
#pragma unroll
    for (int j = 0; j < 4; ++j) {
      const int col = n0 + wc * 64 + j * 16 + fr;
#pragma unroll
      for (int v = 0; v < 4; ++v) {
        if (OUT_BF16) ((unsigned short*)Cv)[(size_t)(row + v) * N + col] = f2bf(acc[i][j][v]);
        else          ((float*)Cv)[(size_t)(row + v) * N + col] = acc[i][j][v];
      }
    }
  }
}

// ---------------------------------------------------------------- RoPE in-place on qkv
// qkv: [4096][3072] bf16; cols 0..2047 q (32 heads x 64), 2048..2559 k (8 x 64).
// Pairs (d, d+32) within each head; q additionally scaled by 0.125 (1/sqrt(64)).
__global__ void rope_kernel(unsigned short* __restrict__ qkv,
                            const float* __restrict__ costab,
                            const float* __restrict__ sintab) {
  int idx = blockIdx.x * blockDim.x + threadIdx.x;
  if (idx >= 4096 * 1280) return;
  int row = idx / 1280;
  int p = idx - row * 1280;
  int s = row & 2047;
  int col, d; bool isq;
  if (p < 1024) { isq = true;  d = p & 31; col = (p >> 5) * 64 + d; }
  else { isq = false; int pk = p - 1024; d = pk & 31; col = 2048 + (pk >> 5) * 64 + d; }
  float c = costab[s * 32 + d], sn = sintab[s * 32 + d];
  unsigned short* base = qkv + (size_t)row * 3072;
  float x1 = bf2f(base[col]), x2 = bf2f(base[col + 32]);
  float o1 = x1 * c - x2 * sn;
  float o2 = x1 * sn + x2 * c;
  if (isq) { o1 *= 0.125f; o2 *= 0.125f; }
  base[col] = f2bf(o1);
  base[col + 32] = f2bf(o2);
}

// ---------------------------------------------------------------- flash attention
// Grid (S/128, H=32, B=2), 256 threads (4 waves). Each wave: 32 q-rows.
// KBLK=32 keys per step; K in LDS [32][64]; V transposed in LDS [64][32];
// P round-trips through per-wave LDS [32][32]. Q pre-scaled by 0.125 in rope.
__global__ __launch_bounds__(256) void flash_attn(const unsigned short* __restrict__ qkv,
                                                  unsigned short* __restrict__ out) {
  __shared__ __align__(16) unsigned short K_lds[32 * 64];
  __shared__ __align__(16) unsigned short Vt_lds[64 * 32];
  __shared__ __align__(16) unsigned short P_lds[4][32 * 32];
  const int tid = threadIdx.x;
  const int wave = tid >> 6, lane = tid & 63;
  const int fq = lane >> 4, fr = lane & 15;
  const int b = blockIdx.z, h = blockIdx.y, qt = blockIdx.x;
  const int kvh = h >> 2;
  const int q0 = qt * 128;
  const int wq0 = q0 + wave * 32;

  // Q fragments in registers: qreg[qf][kk][j] = Q[wq0+qf*16+(l&15)][kk*32+(l>>4)*8+j]
  bf16x8 qreg[2][2];
#pragma unroll
  for (int qf = 0; qf < 2; ++qf)
#pragma unroll
    for (int kk = 0; kk < 2; ++kk)
      qreg[qf][kk] = *(const bf16x8*)(qkv + (size_t)(b * 2048 + wq0 + qf * 16 + fr) * 3072
                                      + h * 64 + kk * 32 + fq * 8);

  f32x4 o_acc[2][4];
  float m_run[2][4], l_run[2][4];
#pragma unroll
  for (int qf = 0; qf < 2; ++qf) {
#pragma unroll
    for (int dc = 0; dc < 4; ++dc) o_acc[qf][dc] = f32x4_zero();
#pragma unroll
    for (int v = 0; v < 4; ++v) { m_run[qf][v] = -INFINITY; l_run[qf][v] = 0.f; }
  }

  const unsigned short* kbase = qkv + (size_t)(b * 2048) * 3072 + 2048 + kvh * 64;
  const unsigned short* vbase = kbase + 512;   // v starts at col 2560
  const int nsteps = (q0 + 128) >> 5;

  for (int st = 0; st < nsteps; ++st) {
    const int k0 = st << 5;
    __syncthreads();
    // K tile: 32x64 bf16 = 4096B = one global_load_lds per thread.
    __builtin_amdgcn_global_load_lds(GPTR(kbase + (size_t)(k0 + (tid >> 3)) * 3072 + ((tid & 7) << 3)),
                                     LPTR(K_lds + wave * 512), 16, 0, 0);
    // V tile transposed: Vt[c][k] = V[k][c]
    {
      bf16x8 vv = *(const bf16x8*)(vbase + (size_t)(k0 + (tid >> 3)) * 3072 + ((tid & 7) << 3));
      const int kk = tid >> 3, c0 = (tid & 7) << 3;
#pragma unroll
      for (int j = 0; j < 8; ++j) Vt_lds[(c0 + j) * 32 + kk] = (unsigned short)vv[j];
    }
    __syncthreads();

    if (k0 <= wq0 + 31) {           // wave-uniform: skip fully-masked tiles
      // ---- S = Q K^T  (rows: q, cols: keys)
      f32x4 s_acc[2][2];
#pragma unroll
      for (int a = 0; a < 2; ++a)
#pragma unroll
        for (int c = 0; c < 2; ++c) s_acc[a][c] = f32x4_zero();
#pragma unroll
      for (int kf = 0; kf < 2; ++kf)
#pragma unroll
        for (int kk = 0; kk < 2; ++kk) {
          bf16x8 kb = *(const bf16x8*)(K_lds + (kf * 16 + fr) * 64 + kk * 32 + fq * 8);
#pragma unroll
          for (int qf = 0; qf < 2; ++qf)
            s_acc[qf][kf] = __builtin_amdgcn_mfma_f32_16x16x32_bf16(qreg[qf][kk], kb, s_acc[qf][kf], 0, 0, 0);
        }
      // ---- causal mask (only straddling tiles)
      if (k0 + 31 > wq0) {
#pragma unroll
        for (int qf = 0; qf < 2; ++qf)
#pragma unroll
          for (int kf = 0; kf < 2; ++kf)
#pragma unroll
            for (int v = 0; v < 4; ++v) {
              int rq = wq0 + qf * 16 + fq * 4 + v;
              int ck = k0 + kf * 16 + fr;
              if (ck > rq) s_acc[qf][kf][v] = -INFINITY;
            }
      }
      // ---- online softmax (rows live across 16 lanes sharing fq)
#pragma unroll
      for (int qf = 0; qf < 2; ++qf) {
#pragma unroll
        for (int v = 0; v < 4; ++v) {
          float pm = fmaxf(s_acc[qf][0][v], s_acc[qf][1][v]);
          pm = fmaxf(pm, __shfl_xor(pm, 1));
          pm = fmaxf(pm, __shfl_xor(pm, 2));
          pm = fmaxf(pm, __shfl_xor(pm, 4));
          pm = fmaxf(pm, __shfl_xor(pm, 8));
          const float mo = m_run[qf][v];
          const float mn = fmaxf(mo, pm);
          m_run[qf][v] = mn;
          const float sc = expf(mo - mn);
          const float p0 = expf(s_acc[qf][0][v] - mn);
          const float p1 = expf(s_acc[qf][1][v] - mn);
          float ps = p0 + p1;
          ps += __shfl_xor(ps, 1);
          ps += __shfl_xor(ps, 2);
          ps += __shfl_xor(ps, 4);
          ps += __shfl_xor(ps, 8);
          l_run[qf][v] = l_run[qf][v] * sc + ps;
#pragma unroll
          for (int dc = 0; dc < 4; ++dc) o_acc[qf][dc][v] *= sc;
          P_lds[wave][(qf * 16 + fq * 4 + v) * 32 + fr]      = f2bf(p0);
          P_lds[wave][(qf * 16 + fq * 4 + v) * 32 + 16 + fr] = f2bf(p1);
        }
      }
      asm volatile("s_waitcnt lgkmcnt(0)" ::: "memory");
      // ---- O += P @ V
#pragma unroll
      for (int qf = 0; qf < 2; ++qf) {
        bf16x8 pa = *(const bf16x8*)(&P_lds[wave][(qf * 16 + fr) * 32 + fq * 8]);
#pragma unroll
        for (int dc = 0; dc < 4; ++dc) {
          bf16x8 vb = *(const bf16x8*)(Vt_lds + (dc * 16 + fr) * 32 + fq * 8);
          o_acc[qf][dc] = __builtin_amdgcn_mfma_f32_16x16x32_bf16(pa, vb, o_acc[qf][dc], 0, 0, 0);
        }
      }
    }
  }

  // ---- epilogue: O / l -> bf16
#pragma unroll
  for (int qf = 0; qf < 2; ++qf)
#pragma unroll
    for (int v = 0; v < 4; ++v) {
      const float inv = 1.0f / l_run[qf][v];
      const size_t row = (size_t)(b * 2048 + wq0 + qf * 16 + fq * 4 + v);
#pragma unroll
      for (int dc = 0; dc < 4; ++dc) {
        const int col = h * 64 + dc * 16 + fr;
        out[row * 2048 + col] = f2bf(o_acc[qf][dc][v] * inv);
      }
    }
}

// ---------------------------------------------------------------- launch
extern "C" void kernel_launch(void* const* d_in, const int* in_sizes, int n_in,
                              void* d_out, int out_size, void* d_ws, size_t ws_size,
                              hipStream_t stream) {
  (void)in_sizes; (void)n_in; (void)out_size; (void)ws_size;
  const float* x  = (const float*)d_in[0];
  const float* wq = (const float*)d_in[1];
  const float* wk = (const float*)d_in[2];
  const float* wv = (const float*)d_in[3];
  const float* wo = (const float*)d_in[4];

  char* wsb = (char*)d_ws;
  // ws layout (bytes):
  //   0        xb [4096][2048] bf16 (16.78MB) -- reused as attn_o after QKV GEMM
  //   16777216 wqkvb [3072][2048] bf16 (12.58MB)
  //   29360128 wob [2048][2048] bf16 (8.39MB)
  //   37748736 qkv [4096][3072] bf16 (25.17MB)
  //   62914560 costab [2048*32] f32 ; 63176704 sintab ; total 63438848
  unsigned short* xb     = (unsigned short*)(wsb);
  unsigned short* attn_o = xb;
  unsigned short* wqkvb  = (unsigned short*)(wsb + 16777216);
  unsigned short* wob    = (unsigned short*)(wsb + 29360128);
  unsigned short* qkv    = (unsigned short*)(wsb + 37748736);
  float* costab          = (float*)(wsb + 62914560);
  float* sintab          = (float*)(wsb + 63176704);

  rope_table_kernel<<<256, 256, 0, stream>>>(costab, sintab);

  f32_to_bf16<<<2048, 256, 0, stream>>>(x,  xb,                 8388608 / 4);
  f32_to_bf16<<<1024, 256, 0, stream>>>(wq, wqkvb,              4194304 / 4);
  f32_to_bf16<<<256,  256, 0, stream>>>(wk, wqkvb + 4194304,    1048576 / 4);
  f32_to_bf16<<<256,  256, 0, stream>>>(wv, wqkvb + 5242880,    1048576 / 4);
  f32_to_bf16<<<1024, 256, 0, stream>>>(wo, wob,                4194304 / 4);

  // qkv = x @ [wq;wk;wv]^T : M=4096, N=3072, K=2048
  gemm_bt<1><<<dim3(24, 32), 256, 0, stream>>>(xb, wqkvb, (void*)qkv, 3072, 2048);

  rope_kernel<<<20480, 256, 0, stream>>>(qkv, costab, sintab);

  flash_attn<<<dim3(16, 32, 2), 256, 0, stream>>>(qkv, attn_o);

  // out = attn @ wo^T : M=4096, N=2048, K=2048 (fp32 out)
  gemm_bt<0><<<dim3(16, 32), 256, 0, stream>>>(attn_o, wob, d_out, 2048, 2048);
}

// Round 2
// 310.148 us; speedup vs baseline: 1.9023x; 1.9023x over previous
//
#include <hip/hip_runtime.h>

typedef __attribute__((ext_vector_type(8))) short bf16x8;
typedef __attribute__((ext_vector_type(4))) float f32x4;
typedef __attribute__((ext_vector_type(4))) unsigned short u16x4;

#define GPTR(p) (const __attribute__((address_space(1))) void*)(p)
#define LPTR(p) (__attribute__((address_space(3))) void*)(p)

static __device__ __forceinline__ unsigned short f2bf(float f) {
  union { float f; unsigned int u; } x; x.f = f;
  unsigned int u = x.u;
  unsigned int r = (u + 0x7fffu + ((u >> 16) & 1u)) >> 16;
  return (unsigned short)r;
}
static __device__ __forceinline__ float bf2f(unsigned short h) {
  union { unsigned int u; float f; } x; x.u = ((unsigned int)h) << 16;
  return x.f;
}
static __device__ __forceinline__ f32x4 f32x4_zero() {
  f32x4 z = {0.f, 0.f, 0.f, 0.f}; return z;
}
static __device__ __forceinline__ unsigned int cvt_pk_bf16(float lo, float hi) {
  unsigned int r;
  asm("v_cvt_pk_bf16_f32 %0, %1, %2" : "=v"(r) : "v"(lo), "v"(hi));
  return r;
}

// ---------------------------------------------------------------- RoPE table
__global__ void rope_table_kernel(float* __restrict__ costab, float* __restrict__ sintab) {
  int i = blockIdx.x * blockDim.x + threadIdx.x;   // 65536 total
  int s = i >> 5, d = i & 31;
  float invf = exp2f(-(float)d * (13.287712379549449f / 32.0f));
  float a = (float)s * invf;
  costab[i] = cosf(a);
  sintab[i] = sinf(a);
}

// ---------------------------------------------------------------- f32 -> bf16
__global__ void f32_to_bf16(const float* __restrict__ src, unsigned short* __restrict__ dst, int n4) {
  int stride = gridDim.x * blockDim.x;
  for (int i = blockIdx.x * blockDim.x + threadIdx.x; i < n4; i += stride) {
    float4 v = ((const float4*)src)[i];
    u16x4 o;
    o.x = f2bf(v.x); o.y = f2bf(v.y); o.z = f2bf(v.z); o.w = f2bf(v.w);
    *(u16x4*)(dst + (size_t)i * 4) = o;
  }
}

// ---------------------------------------------------------------- GEMM C = A @ B^T (m97 structure)
template<int OUT_BF16>
__global__ __launch_bounds__(256) void gemm_bt(const unsigned short* __restrict__ A,
                                               const unsigned short* __restrict__ B,
                                               void* __restrict__ Cv, int N, int K) {
  __shared__ __align__(16) unsigned short lsA[128 * 32];
  __shared__ __align__(16) unsigned short lsB[128 * 32];
  const int tid = threadIdx.x;
  const int wave = tid >> 6, lane = tid & 63;
  const int fq = lane >> 4, fr = lane & 15;
  const int wr = wave >> 1, wc = wave & 1;
  const int m0 = blockIdx.y * 128, n0 = blockIdx.x * 128;

  const unsigned short* ga0 = A + (size_t)(m0 + (tid >> 2)) * K + ((tid & 3) << 3);
  const unsigned short* ga1 = ga0 + (size_t)64 * K;
  const unsigned short* gb0 = B + (size_t)(n0 + (tid >> 2)) * K + ((tid & 3) << 3);
  const unsigned short* gb1 = gb0 + (size_t)64 * K;
  unsigned short* lA0 = lsA + wave * 512;
  unsigned short* lA1 = lsA + 2048 + wave * 512;
  unsigned short* lB0 = lsB + wave * 512;
  unsigned short* lB1 = lsB + 2048 + wave * 512;

  f32x4 acc[4][4];
#pragma unroll
  for (int i = 0; i < 4; ++i)
#pragma unroll
    for (int j = 0; j < 4; ++j) acc[i][j] = f32x4_zero();

  for (int k0 = 0; k0 < K; k0 += 32) {
    __syncthreads();
    __builtin_amdgcn_global_load_lds(GPTR(ga0 + k0), LPTR(lA0), 16, 0, 0);
    __builtin_amdgcn_global_load_lds(GPTR(ga1 + k0), LPTR(lA1), 16, 0, 0);
    __builtin_amdgcn_global_load_lds(GPTR(gb0 + k0), LPTR(lB0), 16, 0, 0);
    __builtin_amdgcn_global_load_lds(GPTR(gb1 + k0), LPTR(lB1), 16, 0, 0);
    __syncthreads();
    bf16x8 af[4], bfr[4];
#pragma unroll
    for (int f = 0; f < 4; ++f) {
      af[f]  = *(const bf16x8*)(lsA + (wr * 64 + f * 16 + fr) * 32 + fq * 8);
      bfr[f] = *(const bf16x8*)(lsB + (wc * 64 + f * 16 + fr) * 32 + fq * 8);
    }
#pragma unroll
    for (int i = 0; i < 4; ++i)
#pragma unroll
      for (int j = 0; j < 4; ++j)
        acc[i][j] = __builtin_amdgcn_mfma_f32_16x16x32_bf16(af[i], bfr[j], acc[i][j], 0, 0, 0);
  }

#pragma unroll
  for (int i = 0; i < 4; ++i) {
    const int row = m0 + wr * 64 + i * 16 + fq * 4;
#pragma unroll
    for (int j = 0; j < 4; ++j) {
      const int col = n0 + wc * 64 + j * 16 + fr;
#pragma unroll
      for (int v = 0; v < 4; ++v) {
        if (OUT_BF16) ((unsigned short*)Cv)[(size_t)(row + v) * N + col] = f2bf(acc[i][j][v]);
        else          ((float*)Cv)[(size_t)(row + v) * N + col] = acc[i][j][v];
      }
    }
  }
}

// ---------------------------------------------------------------- RoPE in-place on qkv
// q scaled by 0.125*log2(e) so attention softmax runs in exp2 domain.
__global__ void rope_kernel(unsigned short* __restrict__ qkv,
                            const float* __restrict__ costab,
                            const float* __restrict__ sintab) {
  int idx = blockIdx.x * blockDim.x + threadIdx.x;
  if (idx >= 4096 * 1280) return;
  int row = idx / 1280;
  int p = idx - row * 1280;
  int s = row & 2047;
  int col, d; bool isq;
  if (p < 1024) { isq = true;  d = p & 31; col = (p >> 5) * 64 + d; }
  else { isq = false; int pk = p - 1024; d = pk & 31; col = 2048 + (pk >> 5) * 64 + d; }
  float c = costab[s * 32 + d], sn = sintab[s * 32 + d];
  unsigned short* base = qkv + (size_t)row * 3072;
  float x1 = bf2f(base[col]), x2 = bf2f(base[col + 32]);
  float o1 = x1 * c - x2 * sn;
  float o2 = x1 * sn + x2 * c;
  if (isq) { o1 *= 0.18033688011112042f; o2 *= 0.18033688011112042f; }  // 0.125*log2(e)
  base[col] = f2bf(o1);
  base[col + 32] = f2bf(o2);
}

// ---------------------------------------------------------------- flash attention (swapped-QK^T)
// Grid (S/128, H=32, B=2), 256 threads (4 waves), 32 q-rows/wave, KBLK=64.
// S^T = mfma(K,Q): lane holds 16 scores (4 keys x 4 kf) for query fr per qf-block.
// O^T += mfma(Vt, P): rescale lane-local. P round-trips via per-wave LDS (cvt_pk packed).
#define KBLK 64
__global__ __launch_bounds__(256) void flash_attn(const unsigned short* __restrict__ qkv,
                                                  unsigned short* __restrict__ out) {
  // K_lds: [64][64] bf16, XOR-swizzled (byte ^= (row&7)<<4 within 128B rows)  : 8 KB
  // Vt_lds: V^T [64 d][64 k] bf16, chunk-swizzled by (k>>3)^(d>>3)            : 8 KB
  // P_lds: per-wave [32 q][72 k-shorts] (36 dwords, 144B rows)                : 18 KB
  __shared__ __align__(16) unsigned short K_lds[64 * 64];
  __shared__ __align__(16) unsigned short Vt_lds[64 * 64];
  __shared__ __align__(16) unsigned int  P_lds[4][32 * 36];

  const int tid = threadIdx.x;
  const int wave = tid >> 6, lane = tid & 63;
  const int fq = lane >> 4, fr = lane & 15;
  const int b = blockIdx.z, h = blockIdx.y;
  const int qt = gridDim.x - 1 - blockIdx.x;       // long blocks first
  const int kvh = h >> 2;
  const int q0 = qt * 128;
  const int wq0 = q0 + wave * 32;

  // Q fragments (b-operand): B[j=fr][k] = Q[wq0+qf*16+fr][kk*32+fq*8+j]
  bf16x8 qreg[2][2];
#pragma unroll
  for (int qf = 0; qf < 2; ++qf)
#pragma unroll
    for (int kk = 0; kk < 2; ++kk)
      qreg[qf][kk] = *(const bf16x8*)(qkv + (size_t)(b * 2048 + wq0 + qf * 16 + fr) * 3072
                                      + h * 64 + kk * 32 + fq * 8);

  f32x4 o_acc[4][2];     // [dc][qf] : O^T block rows d=dc*16+fq*4+v, col q=fr
  float m_run[2], l_run[2];
#pragma unroll
  for (int dc = 0; dc < 4; ++dc) { o_acc[dc][0] = f32x4_zero(); o_acc[dc][1] = f32x4_zero(); }
  m_run[0] = m_run[1] = -1e30f;
  l_run[0] = l_run[1] = 0.f;

  const char* kgbase = (const char*)qkv + (size_t)(b * 2048) * 6144 + 4096 + kvh * 128;
  const unsigned short* vgbase = qkv + (size_t)(b * 2048) * 3072 + 2560 + kvh * 64;
  const int nsteps = (q0 + 128) >> 6;

  for (int st = 0; st < nsteps; ++st) {
    const int k0 = st << 6;
    __syncthreads();
    // ---- stage K (global_load_lds, pre-swizzled source)
#pragma unroll
    for (int r = 0; r < 2; ++r) {
      const int row = (tid >> 3) + r * 32;
      const int cb = (tid & 7) << 4;
      __builtin_amdgcn_global_load_lds(GPTR(kgbase + (size_t)(k0 + row) * 6144 + (cb ^ ((row & 7) << 4))),
                                       LPTR((char*)K_lds + r * 4096 + wave * 1024), 16, 0, 0);
    }
    // ---- stage V transposed (reg -> swizzled scalar LDS writes)
#pragma unroll
    for (int r = 0; r < 2; ++r) {
      const int k = (tid >> 3) + r * 32;
      const int c0 = (tid & 7) << 3;
      bf16x8 vv = *(const bf16x8*)(vgbase + (size_t)(k0 + k) * 3072 + c0);
#pragma unroll
      for (int j = 0; j < 8; ++j) {
        const int d = c0 + j;
        Vt_lds[d * 64 + (k & 7) + ((((k >> 3) ^ (d >> 3)) & 7) << 3)] = (unsigned short)vv[j];
      }
    }
    __syncthreads();

    if (k0 <= wq0 + 31) {
      // ---- S^T = K @ Q^T : s[qf][kf][v] = S[key=k0+kf*16+fq*4+v][q=wq0+qf*16+fr]
      f32x4 s[2][4];
#pragma unroll
      for (int qf = 0; qf < 2; ++qf)
#pragma unroll
        for (int kf = 0; kf < 4; ++kf) s[qf][kf] = f32x4_zero();
#pragma unroll
      for (int kf = 0; kf < 4; ++kf) {
        const int krow = kf * 16 + fr;
        const char* kb = (const char*)K_lds + krow * 128;
        const int swz = (krow & 7) << 4;
        bf16x8 kf0 = *(const bf16x8*)(kb + ((fq * 16) ^ swz));
        bf16x8 kf1 = *(const bf16x8*)(kb + ((64 + fq * 16) ^ swz));
#pragma unroll
        for (int qf = 0; qf < 2; ++qf) {
          s[qf][kf] = __builtin_amdgcn_mfma_f32_16x16x32_bf16(kf0, qreg[qf][0], s[qf][kf], 0, 0, 0);
          s[qf][kf] = __builtin_amdgcn_mfma_f32_16x16x32_bf16(kf1, qreg[qf][1], s[qf][kf], 0, 0, 0);
        }
      }
      // ---- causal mask (straddling tiles only)
      if (k0 + 63 > wq0) {
#pragma unroll
        for (int qf = 0; qf < 2; ++qf) {
          const int q = wq0 + qf * 16 + fr;
#pragma unroll
          for (int kf = 0; kf < 4; ++kf)
#pragma unroll
            for (int v = 0; v < 4; ++v) {
              const int key = k0 + kf * 16 + fq * 4 + v;
              if (key > q) s[qf][kf][v] = -1e30f;
            }
        }
      }
      // ---- online softmax (exp2 domain; per-query state is lane-local)
#pragma unroll
      for (int qf = 0; qf < 2; ++qf) {
        float t = s[qf][0][0];
#pragma unroll
        for (int kf = 0; kf < 4; ++kf)
#pragma unroll
          for (int v = 0; v < 4; ++v) t = fmaxf(t, s[qf][kf][v]);
        t = fmaxf(t, __shfl_xor(t, 16));
        t = fmaxf(t, __shfl_xor(t, 32));
        const float mo = m_run[qf];
        const float mn = fmaxf(mo, t);
        const float sc = __builtin_amdgcn_exp2f(mo - mn);
        m_run[qf] = mn;
        float ps = 0.f;
#pragma unroll
        for (int kf = 0; kf < 4; ++kf)
#pragma unroll
          for (int v = 0; v < 4; ++v) {
            const float p = __builtin_amdgcn_exp2f(s[qf][kf][v] - mn);
            s[qf][kf][v] = p;
            ps += p;
          }
        ps += __shfl_xor(ps, 16);
        ps += __shfl_xor(ps, 32);
        l_run[qf] = l_run[qf] * sc + ps;
#pragma unroll
        for (int dc = 0; dc < 4; ++dc) o_acc[dc][qf] *= sc;
        // pack P row (q-local = qf*16+fr), cols kf*16+fq*4..+3
        unsigned int* pbase = &P_lds[wave][(qf * 16 + fr) * 36];
#pragma unroll
        for (int kf = 0; kf < 4; ++kf) {
          uint2 w;
          w.x = cvt_pk_bf16(s[qf][kf][0], s[qf][kf][1]);
          w.y = cvt_pk_bf16(s[qf][kf][2], s[qf][kf][3]);
          *(uint2*)(pbase + kf * 8 + fq * 2) = w;
        }
      }
      // ---- O^T += V^T @ P
#pragma unroll
      for (int kk = 0; kk < 2; ++kk) {
        bf16x8 pa0 = *(const bf16x8*)((const char*)&P_lds[wave][0] + (fr) * 144 + kk * 64 + fq * 16);
        bf16x8 pa1 = *(const bf16x8*)((const char*)&P_lds[wave][0] + (16 + fr) * 144 + kk * 64 + fq * 16);
#pragma unroll
        for (int dc = 0; dc < 4; ++dc) {
          const int d = dc * 16 + fr;
          bf16x8 vt = *(const bf16x8*)(Vt_lds + d * 64 + ((((kk * 4 + fq) ^ (d >> 3)) & 7) << 3));
          o_acc[dc][0] = __builtin_amdgcn_mfma_f32_16x16x32_bf16(vt, pa0, o_acc[dc][0], 0, 0, 0);
          o_acc[dc][1] = __builtin_amdgcn_mfma_f32_16x16x32_bf16(vt, pa1, o_acc[dc][1], 0, 0, 0);
        }
      }
    }
  }

  // ---- epilogue: out[q][d] = O^T[d][q] / l
#pragma unroll
  for (int qf = 0; qf < 2; ++qf) {
    const float inv = 1.0f / l_run[qf];
    const size_t row = (size_t)(b * 2048 + wq0 + qf * 16 + fr);
#pragma unroll
    for (int dc = 0; dc < 4; ++dc) {
      u16x4 o;
#pragma unroll
      for (int v = 0; v < 4; ++v) o[v] = f2bf(o_acc[dc][qf][v] * inv);
      *(u16x4*)(out + row * 2048 + h * 64 + dc * 16 + fq * 4) = o;
    }
  }
}

// ---------------------------------------------------------------- launch
extern "C" void kernel_launch(void* const* d_in, const int* in_sizes, int n_in,
                              void* d_out, int out_size, void* d_ws, size_t ws_size,
                              hipStream_t stream) {
  (void)in_sizes; (void)n_in; (void)out_size; (void)ws_size;
  const float* x  = (const float*)d_in[0];
  const float* wq = (const float*)d_in[1];
  const float* wk = (const float*)d_in[2];
  const float* wv = (const float*)d_in[3];
  const float* wo = (const float*)d_in[4];

  char* wsb = (char*)d_ws;
  unsigned short* xb     = (unsigned short*)(wsb);
  unsigned short* attn_o = xb;
  unsigned short* wqkvb  = (unsigned short*)(wsb + 16777216);
  unsigned short* wob    = (unsigned short*)(wsb + 29360128);
  unsigned short* qkv    = (unsigned short*)(wsb + 37748736);
  float* costab          = (float*)(wsb + 62914560);
  float* sintab          = (float*)(wsb + 63176704);

  rope_table_kernel<<<256, 256, 0, stream>>>(costab, sintab);

  f32_to_bf16<<<2048, 256, 0, stream>>>(x,  xb,                 8388608 / 4);
  f32_to_bf16<<<1024, 256, 0, stream>>>(wq, wqkvb,              4194304 / 4);
  f32_to_bf16<<<256,  256, 0, stream>>>(wk, wqkvb + 4194304,    1048576 / 4);
  f32_to_bf16<<<256,  256, 0, stream>>>(wv, wqkvb + 5242880,    1048576 / 4);
  f32_to_bf16<<<1024, 256, 0, stream>>>(wo, wob,                4194304 / 4);

  // qkv = x @ [wq;wk;wv]^T : M=4096, N=3072, K=2048
  gemm_bt<1><<<dim3(24, 32), 256, 0, stream>>>(xb, wqkvb, (void*)qkv, 3072, 2048);

  rope_kernel<<<20480, 256, 0, stream>>>(qkv, costab, sintab);

  flash_attn<<<dim3(16, 32, 2), 256, 0, stream>>>(qkv, attn_o);

  // out = attn @ wo^T : M=4096, N=2048, K=2048 (fp32 out)
  gemm_bt<0><<<dim3(16, 32), 256, 0, stream>>>(attn_o, wob, d_out, 2048, 2048);
}

// Round 3
// 276.821 us; speedup vs baseline: 2.1313x; 1.1204x over previous
//
#include <hip/hip_runtime.h>

typedef __attribute__((ext_vector_type(8))) short bf16x8;
typedef __attribute__((ext_vector_type(4))) float f32x4;
typedef __attribute__((ext_vector_type(4))) unsigned short u16x4;

#define GPTR(p) (const __attribute__((address_space(1))) void*)(p)
#define LPTR(p) (__attribute__((address_space(3))) void*)(p)

static __device__ __forceinline__ unsigned short f2bf(float f) {
  union { float f; unsigned int u; } x; x.f = f;
  unsigned int u = x.u;
  unsigned int r = (u + 0x7fffu + ((u >> 16) & 1u)) >> 16;
  return (unsigned short)r;
}
static __device__ __forceinline__ float bf2f(unsigned short h) {
  union { unsigned int u; float f; } x; x.u = ((unsigned int)h) << 16;
  return x.f;
}
static __device__ __forceinline__ f32x4 f32x4_zero() {
  f32x4 z = {0.f, 0.f, 0.f, 0.f}; return z;
}
static __device__ __forceinline__ unsigned int cvt_pk_bf16(float lo, float hi) {
  unsigned int r;
  asm("v_cvt_pk_bf16_f32 %0, %1, %2" : "=v"(r) : "v"(lo), "v"(hi));
  return r;
}

// ---------------------------------------------------------------- RoPE table
__global__ void rope_table_kernel(float* __restrict__ costab, float* __restrict__ sintab) {
  int i = blockIdx.x * blockDim.x + threadIdx.x;   // 65536 total
  int s = i >> 5, d = i & 31;
  float invf = exp2f(-(float)d * (13.287712379549449f / 32.0f));
  float a = (float)s * invf;
  costab[i] = cosf(a);
  sintab[i] = sinf(a);
}

// ---------------------------------------------------------------- f32 -> bf16
__global__ void f32_to_bf16(const float* __restrict__ src, unsigned short* __restrict__ dst, int n4) {
  int stride = gridDim.x * blockDim.x;
  for (int i = blockIdx.x * blockDim.x + threadIdx.x; i < n4; i += stride) {
    float4 v = ((const float4*)src)[i];
    u16x4 o;
    o.x = f2bf(v.x); o.y = f2bf(v.y); o.z = f2bf(v.z); o.w = f2bf(v.w);
    *(u16x4*)(dst + (size_t)i * 4) = o;
  }
}

// ---------------------------------------------------------------- GEMM C = A @ B^T (m97 structure)
template<int OUT_BF16>
__global__ __launch_bounds__(256) void gemm_bt(const unsigned short* __restrict__ A,
                                               const unsigned short* __restrict__ B,
                                               void* __restrict__ Cv, int N, int K) {
  __shared__ __align__(16) unsigned short lsA[128 * 32];
  __shared__ __align__(16) unsigned short lsB[128 * 32];
  const int tid = threadIdx.x;
  const int wave = tid >> 6, lane = tid & 63;
  const int fq = lane >> 4, fr = lane & 15;
  const int wr = wave >> 1, wc = wave & 1;
  const int m0 = blockIdx.y * 128, n0 = blockIdx.x * 128;

  const unsigned short* ga0 = A + (size_t)(m0 + (tid >> 2)) * K + ((tid & 3) << 3);
  const unsigned short* ga1 = ga0 + (size_t)64 * K;
  const unsigned short* gb0 = B + (size_t)(n0 + (tid >> 2)) * K + ((tid & 3) << 3);
  const unsigned short* gb1 = gb0 + (size_t)64 * K;
  unsigned short* lA0 = lsA + wave * 512;
  unsigned short* lA1 = lsA + 2048 + wave * 512;
  unsigned short* lB0 = lsB + wave * 512;
  unsigned short* lB1 = lsB + 2048 + wave * 512;

  f32x4 acc[4][4];
#pragma unroll
  for (int i = 0; i < 4; ++i)
#pragma unroll
    for (int j = 0; j < 4; ++j) acc[i][j] = f32x4_zero();

  for (int k0 = 0; k0 < K; k0 += 32) {
    __syncthreads();
    __builtin_amdgcn_global_load_lds(GPTR(ga0 + k0), LPTR(lA0), 16, 0, 0);
    __builtin_amdgcn_global_load_lds(GPTR(ga1 + k0), LPTR(lA1), 16, 0, 0);
    __builtin_amdgcn_global_load_lds(GPTR(gb0 + k0), LPTR(lB0), 16, 0, 0);
    __builtin_amdgcn_global_load_lds(GPTR(gb1 + k0), LPTR(lB1), 16, 0, 0);
    __syncthreads();
    bf16x8 af[4], bfr[4];
#pragma unroll
    for (int f = 0; f < 4; ++f) {
      af[f]  = *(const bf16x8*)(lsA + (wr * 64 + f * 16 + fr) * 32 + fq * 8);
      bfr[f] = *(const bf16x8*)(lsB + (wc * 64 + f * 16 + fr) * 32 + fq * 8);
    }
#pragma unroll
    for (int i = 0; i < 4; ++i)
#pragma unroll
      for (int j = 0; j < 4; ++j)
        acc[i][j] = __builtin_amdgcn_mfma_f32_16x16x32_bf16(af[i], bfr[j], acc[i][j], 0, 0, 0);
  }

#pragma unroll
  for (int i = 0; i < 4; ++i) {
    const int row = m0 + wr * 64 + i * 16 + fq * 4;
#pragma unroll
    for (int j = 0; j < 4; ++j) {
      const int col = n0 + wc * 64 + j * 16 + fr;
#pragma unroll
      for (int v = 0; v < 4; ++v) {
        if (OUT_BF16) ((unsigned short*)Cv)[(size_t)(row + v) * N + col] = f2bf(acc[i][j][v]);
        else          ((float*)Cv)[(size_t)(row + v) * N + col] = acc[i][j][v];
      }
    }
  }
}

// ---------------------------------------------------------------- RoPE in-place on qkv
__global__ void rope_kernel(unsigned short* __restrict__ qkv,
                            const float* __restrict__ costab,
                            const float* __restrict__ sintab) {
  int idx = blockIdx.x * blockDim.x + threadIdx.x;
  if (idx >= 4096 * 1280) return;
  int row = idx / 1280;
  int p = idx - row * 1280;
  int s = row & 2047;
  int col, d; bool isq;
  if (p < 1024) { isq = true;  d = p & 31; col = (p >> 5) * 64 + d; }
  else { isq = false; int pk = p - 1024; d = pk & 31; col = 2048 + (pk >> 5) * 64 + d; }
  float c = costab[s * 32 + d], sn = sintab[s * 32 + d];
  unsigned short* base = qkv + (size_t)row * 3072;
  float x1 = bf2f(base[col]), x2 = bf2f(base[col + 32]);
  float o1 = x1 * c - x2 * sn;
  float o2 = x1 * sn + x2 * c;
  if (isq) { o1 *= 0.18033688011112042f; o2 *= 0.18033688011112042f; }  // 0.125*log2(e)
  base[col] = f2bf(o1);
  base[col + 32] = f2bf(o2);
}

// ---------------------------------------------------------------- flash attention (8-wave, dbuf)
// Grid (S/256, H=32, B=2), 512 threads (8 waves), 32 q-rows/wave, KBLK=64.
// K: dbuf [64][64] bf16, XOR swizzle (row&7)<<4, staged by waves 4-7 via global_load_lds.
// Vt: dbuf V^T [64 d][64 k] bf16, swizzle key (d&7)^(d>>3), staged by waves 0-3 (T14 split).
// P: per-wave [32][64] bf16, XOR swizzle (row&7)<<4.
__global__ __launch_bounds__(512, 4) void flash_attn(const unsigned short* __restrict__ qkv,
                                                     unsigned short* __restrict__ out) {
  __shared__ __align__(16) char K_sh[2 * 8192];
  __shared__ __align__(16) char V_sh[2 * 8192];
  __shared__ __align__(16) char P_sh[8 * 4096];

  const int tid = threadIdx.x;
  const int wave = tid >> 6, lane = tid & 63;
  const int fq = lane >> 4, fr = lane & 15;
  const int b = blockIdx.z, h = blockIdx.y;
  const int qt = gridDim.x - 1 - blockIdx.x;       // long blocks first
  const int kvh = h >> 2;
  const int q0 = qt * 256;
  const int wq0 = q0 + wave * 32;
  char* Pw = P_sh + wave * 4096;

  // Q fragments (b-operand): B[col=fr][k=fq*8+j]
  bf16x8 qreg[2][2];
#pragma unroll
  for (int qf = 0; qf < 2; ++qf)
#pragma unroll
    for (int kk = 0; kk < 2; ++kk)
      qreg[qf][kk] = *(const bf16x8*)(qkv + (size_t)(b * 2048 + wq0 + qf * 16 + fr) * 3072
                                      + h * 64 + kk * 32 + fq * 8);

  f32x4 o_acc[4][2];     // [dc][qf] : O^T rows d=dc*16+fq*4+v, col q=fr
  float m_run[2], l_run[2];
#pragma unroll
  for (int dc = 0; dc < 4; ++dc) { o_acc[dc][0] = f32x4_zero(); o_acc[dc][1] = f32x4_zero(); }
  m_run[0] = m_run[1] = -1e30f;
  l_run[0] = l_run[1] = 0.f;

  const char* kgbase = (const char*)qkv + (size_t)(b * 2048) * 6144 + 4096 + kvh * 128;
  const unsigned short* vgbase = qkv + (size_t)(b * 2048) * 3072 + 2560 + kvh * 64;
  const int nsteps = (q0 + 256) >> 6;

  // V-stage thread mapping (waves 0-3): 2 k-rows x 8 d per thread
  const int vk2 = (tid >> 3) << 1;          // 0..62 even (valid when tid<256)
  const int vc0 = (tid & 7) << 3;
  // K-stage thread mapping (waves 4-7)
  const int kt = tid - 256;                 // 0..255 (valid when tid>=256)

  // ---------------- prologue: stage tile 0 into buf 0
  {
    if (wave < 4) {
      bf16x8 vv0 = *(const bf16x8*)(vgbase + (size_t)vk2 * 3072 + vc0);
      bf16x8 vv1 = *(const bf16x8*)(vgbase + (size_t)(vk2 + 1) * 3072 + vc0);
#pragma unroll
      for (int j = 0; j < 8; ++j) {
        const int d = vc0 + j;
        const int G = ((d & 7) ^ (d >> 3)) & 7;
        unsigned int w = ((unsigned int)(unsigned short)vv0[j]) |
                         (((unsigned int)(unsigned short)vv1[j]) << 16);
        *(unsigned int*)(V_sh + (d << 7) + ((vk2 << 1) ^ (G << 4))) = w;
      }
    } else {
#pragma unroll
      for (int ld = 0; ld < 2; ++ld) {
        const int row = (kt >> 3) + (ld << 5);
        const int cb = ((kt & 7) << 4) ^ ((row & 7) << 4);
        __builtin_amdgcn_global_load_lds(GPTR(kgbase + (size_t)row * 6144 + cb),
                                         LPTR(K_sh + kt * 16 + ld * 4096), 16, 0, 0);
      }
    }
  }
  __syncthreads();

  int buf = 0;
  for (int st = 0; st < nsteps; ++st) {
    const int k0 = st << 6;
    const bool has_next = (st + 1) < nsteps;
    bf16x8 vv0, vv1;
    // ---- issue next-tile loads (T14 issue-early)
    if (has_next) {
      const int k0n = k0 + 64;
      if (wave < 4) {
        vv0 = *(const bf16x8*)(vgbase + (size_t)(k0n + vk2) * 3072 + vc0);
        vv1 = *(const bf16x8*)(vgbase + (size_t)(k0n + vk2 + 1) * 3072 + vc0);
      } else {
        char* Kn = K_sh + (buf ^ 1) * 8192;
#pragma unroll
        for (int ld = 0; ld < 2; ++ld) {
          const int row = (kt >> 3) + (ld << 5);
          const int cb = ((kt & 7) << 4) ^ ((row & 7) << 4);
          __builtin_amdgcn_global_load_lds(GPTR(kgbase + (size_t)(k0n + row) * 6144 + cb),
                                           LPTR(Kn + kt * 16 + ld * 4096), 16, 0, 0);
        }
      }
    }

    // ---- compute on current buffer
    if (k0 <= wq0 + 31) {
      const char* Kb = K_sh + buf * 8192;
      const char* Vb = V_sh + buf * 8192;
      f32x4 s[2][4];
#pragma unroll
      for (int qf = 0; qf < 2; ++qf)
#pragma unroll
        for (int kf = 0; kf < 4; ++kf) s[qf][kf] = f32x4_zero();
#pragma unroll
      for (int kf = 0; kf < 4; ++kf) {
        const int krow = kf * 16 + fr;
        const int swz = (krow & 7) << 4;
        bf16x8 ka = *(const bf16x8*)(Kb + krow * 128 + ((fq * 16) ^ swz));
        bf16x8 kb = *(const bf16x8*)(Kb + krow * 128 + ((64 + fq * 16) ^ swz));
#pragma unroll
        for (int qf = 0; qf < 2; ++qf) {
          s[qf][kf] = __builtin_amdgcn_mfma_f32_16x16x32_bf16(ka, qreg[qf][0], s[qf][kf], 0, 0, 0);
          s[qf][kf] = __builtin_amdgcn_mfma_f32_16x16x32_bf16(kb, qreg[qf][1], s[qf][kf], 0, 0, 0);
        }
      }
      // causal mask (straddling tiles only)
      if (k0 + 63 > wq0) {
#pragma unroll
        for (int qf = 0; qf < 2; ++qf) {
          const int q = wq0 + qf * 16 + fr;
#pragma unroll
          for (int kf = 0; kf < 4; ++kf)
#pragma unroll
            for (int v = 0; v < 4; ++v) {
              const int key = k0 + kf * 16 + fq * 4 + v;
              if (key > q) s[qf][kf][v] = -1e30f;
            }
        }
      }
      // online softmax (exp2 domain, lane-local per query)
#pragma unroll
      for (int qf = 0; qf < 2; ++qf) {
        float t = s[qf][0][0];
#pragma unroll
        for (int kf = 0; kf < 4; ++kf)
#pragma unroll
          for (int v = 0; v < 4; ++v) t = fmaxf(t, s[qf][kf][v]);
        t = fmaxf(t, __shfl_xor(t, 16));
        t = fmaxf(t, __shfl_xor(t, 32));
        const float mo = m_run[qf];
        const float mn = fmaxf(mo, t);
        const float sc = __builtin_amdgcn_exp2f(mo - mn);
        m_run[qf] = mn;
        float ps = 0.f;
#pragma unroll
        for (int kf = 0; kf < 4; ++kf)
#pragma unroll
          for (int v = 0; v < 4; ++v) {
            const float p = __builtin_amdgcn_exp2f(s[qf][kf][v] - mn);
            s[qf][kf][v] = p;
            ps += p;
          }
        ps += __shfl_xor(ps, 16);
        ps += __shfl_xor(ps, 32);
        l_run[qf] = l_run[qf] * sc + ps;
#pragma unroll
        for (int dc = 0; dc < 4; ++dc) o_acc[dc][qf] *= sc;
        // pack P (row = qf*16+fr), swizzled
        const int r = qf * 16 + fr;
        const int rswz = (r & 7) << 4;
#pragma unroll
        for (int kf = 0; kf < 4; ++kf) {
          uint2 w;
          w.x = cvt_pk_bf16(s[qf][kf][0], s[qf][kf][1]);
          w.y = cvt_pk_bf16(s[qf][kf][2], s[qf][kf][3]);
          *(uint2*)(Pw + r * 128 + ((kf * 32 + fq * 8) ^ rswz)) = w;
        }
      }
      asm volatile("s_waitcnt lgkmcnt(0)" ::: "memory");
      __builtin_amdgcn_sched_barrier(0);
      // O^T += V^T @ P
      const int fswz = (fr & 7) << 4;
#pragma unroll
      for (int kk = 0; kk < 2; ++kk) {
        bf16x8 pa0 = *(const bf16x8*)(Pw + fr * 128 + ((kk * 64 + fq * 16) ^ fswz));
        bf16x8 pa1 = *(const bf16x8*)(Pw + (16 + fr) * 128 + ((kk * 64 + fq * 16) ^ fswz));
#pragma unroll
        for (int dc = 0; dc < 4; ++dc) {
          const int d = dc * 16 + fr;
          const int G = ((d & 7) ^ (d >> 3)) & 7;
          bf16x8 vt = *(const bf16x8*)(Vb + d * 128 + ((kk * 64 + fq * 16) ^ (G << 4)));
          o_acc[dc][0] = __builtin_amdgcn_mfma_f32_16x16x32_bf16(vt, pa0, o_acc[dc][0], 0, 0, 0);
          o_acc[dc][1] = __builtin_amdgcn_mfma_f32_16x16x32_bf16(vt, pa1, o_acc[dc][1], 0, 0, 0);
        }
      }
    }

    // ---- write next V tile (T14 write-late)
    if (has_next && wave < 4) {
      char* Vn = V_sh + (buf ^ 1) * 8192;
#pragma unroll
      for (int j = 0; j < 8; ++j) {
        const int d = vc0 + j;
        const int G = ((d & 7) ^ (d >> 3)) & 7;
        unsigned int w = ((unsigned int)(unsigned short)vv0[j]) |
                         (((unsigned int)(unsigned short)vv1[j]) << 16);
        *(unsigned int*)(Vn + (d << 7) + ((vk2 << 1) ^ (G << 4))) = w;
      }
    }
    __syncthreads();
    buf ^= 1;
  }

  // ---- epilogue: out[q][d] = O^T[d][q] / l
#pragma unroll
  for (int qf = 0; qf < 2; ++qf) {
    const float inv = 1.0f / l_run[qf];
    const size_t row = (size_t)(b * 2048 + wq0 + qf * 16 + fr);
#pragma unroll
    for (int dc = 0; dc < 4; ++dc) {
      u16x4 o;
#pragma unroll
      for (int v = 0; v < 4; ++v) o[v] = f2bf(o_acc[dc][qf][v] * inv);
      *(u16x4*)(out + row * 2048 + h * 64 + dc * 16 + fq * 4) = o;
    }
  }
}

// ---------------------------------------------------------------- launch
extern "C" void kernel_launch(void* const* d_in, const int* in_sizes, int n_in,
                              void* d_out, int out_size, void* d_ws, size_t ws_size,
                              hipStream_t stream) {
  (void)in_sizes; (void)n_in; (void)out_size; (void)ws_size;
  const float* x  = (const float*)d_in[0];
  const float* wq = (const float*)d_in[1];
  const float* wk = (const float*)d_in[2];
  const float* wv = (const float*)d_in[3];
  const float* wo = (const float*)d_in[4];

  char* wsb = (char*)d_ws;
  unsigned short* xb     = (unsigned short*)(wsb);
  unsigned short* attn_o = xb;
  unsigned short* wqkvb  = (unsigned short*)(wsb + 16777216);
  unsigned short* wob    = (unsigned short*)(wsb + 29360128);
  unsigned short* qkv    = (unsigned short*)(wsb + 37748736);
  float* costab          = (float*)(wsb + 62914560);
  float* sintab          = (float*)(wsb + 63176704);

  rope_table_kernel<<<256, 256, 0, stream>>>(costab, sintab);

  f32_to_bf16<<<2048, 256, 0, stream>>>(x,  xb,                 8388608 / 4);
  f32_to_bf16<<<1024, 256, 0, stream>>>(wq, wqkvb,              4194304 / 4);
  f32_to_bf16<<<256,  256, 0, stream>>>(wk, wqkvb + 4194304,    1048576 / 4);
  f32_to_bf16<<<256,  256, 0, stream>>>(wv, wqkvb + 5242880,    1048576 / 4);
  f32_to_bf16<<<1024, 256, 0, stream>>>(wo, wob,                4194304 / 4);

  // qkv = x @ [wq;wk;wv]^T : M=4096, N=3072, K=2048
  gemm_bt<1><<<dim3(24, 32), 256, 0, stream>>>(xb, wqkvb, (void*)qkv, 3072, 2048);

  rope_kernel<<<20480, 256, 0, stream>>>(qkv, costab, sintab);

  flash_attn<<<dim3(8, 32, 2), 512, 0, stream>>>(qkv, attn_o);

  // out = attn @ wo^T : M=4096, N=2048, K=2048 (fp32 out)
  gemm_bt<0><<<dim3(16, 32), 256, 0, stream>>>(attn_o, wob, d_out, 2048, 2048);
}

// Round 5
// 260.100 us; speedup vs baseline: 2.2683x; 1.0643x over previous
//
#include <hip/hip_runtime.h>

typedef __attribute__((ext_vector_type(8))) short bf16x8;
typedef __attribute__((ext_vector_type(4))) float f32x4;
typedef __attribute__((ext_vector_type(4))) unsigned short u16x4;

#define GPTR(p) (const __attribute__((address_space(1))) void*)(p)
#define LPTR(p) (__attribute__((address_space(3))) void*)(p)

static __device__ __forceinline__ unsigned short f2bf(float f) {
  union { float f; unsigned int u; } x; x.f = f;
  unsigned int u = x.u;
  unsigned int r = (u + 0x7fffu + ((u >> 16) & 1u)) >> 16;
  return (unsigned short)r;
}
static __device__ __forceinline__ float bf2f(unsigned short h) {
  union { unsigned int u; float f; } x; x.u = ((unsigned int)h) << 16;
  return x.f;
}
static __device__ __forceinline__ f32x4 f32x4_zero() {
  f32x4 z = {0.f, 0.f, 0.f, 0.f}; return z;
}
static __device__ __forceinline__ unsigned int cvt_pk_bf16(float lo, float hi) {
  unsigned int r;
  asm("v_cvt_pk_bf16_f32 %0, %1, %2" : "=v"(r) : "v"(lo), "v"(hi));
  return r;
}

// ---------------------------------------------------------------- RoPE table
__global__ void rope_table_kernel(float* __restrict__ costab, float* __restrict__ sintab) {
  int i = blockIdx.x * blockDim.x + threadIdx.x;   // 65536 total
  int s = i >> 5, d = i & 31;
  float invf = exp2f(-(float)d * (13.287712379549449f / 32.0f));
  float a = (float)s * invf;
  costab[i] = cosf(a);
  sintab[i] = sinf(a);
}

// ---------------------------------------------------------------- f32 -> bf16
__global__ void f32_to_bf16(const float* __restrict__ src, unsigned short* __restrict__ dst, int n4) {
  int stride = gridDim.x * blockDim.x;
  for (int i = blockIdx.x * blockDim.x + threadIdx.x; i < n4; i += stride) {
    float4 v = ((const float4*)src)[i];
    u16x4 o;
    o.x = f2bf(v.x); o.y = f2bf(v.y); o.z = f2bf(v.z); o.w = f2bf(v.w);
    *(u16x4*)(dst + (size_t)i * 4) = o;
  }
}

// ---------------------------------------------------------------- 8-wave 4-phase GEMM C = A @ B^T
// BM = FM*32, BN = 256, BK = 64. 512 threads (2M x 4N waves). Per-wave output
// (FM*16) x 64 = FM x 4 fragments of 16x16x32 MFMA. LDS: A/B double-buffered,
// rows 128B, XOR-swizzled ((row&7)<<4) via pre-swizzled global_load_lds source.
// Counted vmcnt(2) once per K-tile at phase 0; raw s_barrier elsewhere (no drain).
template<int FM, int OUT_BF16>
__global__ __launch_bounds__(512, 2) void gemm8p(const unsigned short* __restrict__ A,
                                                 const unsigned short* __restrict__ B,
                                                 void* __restrict__ Cv,
                                                 int M, int N, int K, int nbx) {
  constexpr int BM = FM * 32;
  constexpr int MH = FM / 2;
  constexpr int ABYTES = BM * 128;      // per buffer
  constexpr int BBYTES = 256 * 128;
  __shared__ __align__(16) char lds_all[2 * ABYTES + 2 * BBYTES];
  char* lsA = lds_all;
  char* lsB = lds_all + 2 * ABYTES;

  const int tid = threadIdx.x;
  const int wave = tid >> 6, lane = tid & 63;
  const int fq = lane >> 4, fr = lane & 15;
  const int wr = wave >> 2, wc = wave & 3;

  // bijective XCD swizzle (gridDim.x % 8 == 0 by construction)
  const int nwg = gridDim.x;
  const int q8 = nwg >> 3;
  const int sw = (blockIdx.x & 7) * q8 + (blockIdx.x >> 3);
  const int by = sw / nbx;
  const int bx = sw - by * nbx;
  const int m0 = by * BM, n0 = bx * 256;

  // staging geometry: thread covers 16B; rows arow & arow+64 of a 128-row half
  const int arow = tid >> 3;
  const int scol = (((tid & 7) ^ (arow & 7)) << 4);   // pre-swizzled source col byte

#define STAGE_A(bufv, kt, h)                                                                  \
  do {                                                                                        \
    const char* src_ = (const char*)A + ((size_t)(m0 + (h) * 128 + arow) * K + (kt) * 64) * 2 + scol; \
    char* dst_ = lsA + (bufv) * ABYTES + (h) * 16384 + tid * 16;                              \
    __builtin_amdgcn_global_load_lds(GPTR(src_), LPTR(dst_), 16, 0, 0);                       \
    __builtin_amdgcn_global_load_lds(GPTR(src_ + (size_t)64 * K * 2), LPTR(dst_ + 8192), 16, 0, 0); \
  } while (0)
#define STAGE_B(bufv, kt, h)                                                                  \
  do {                                                                                        \
    const char* src_ = (const char*)B + ((size_t)(n0 + (h) * 128 + arow) * K + (kt) * 64) * 2 + scol; \
    char* dst_ = lsB + (bufv) * BBYTES + (h) * 16384 + tid * 16;                              \
    __builtin_amdgcn_global_load_lds(GPTR(src_), LPTR(dst_), 16, 0, 0);                       \
    __builtin_amdgcn_global_load_lds(GPTR(src_ + (size_t)64 * K * 2), LPTR(dst_ + 8192), 16, 0, 0); \
  } while (0)

  f32x4 acc[FM][4];
#pragma unroll
  for (int i = 0; i < FM; ++i)
#pragma unroll
    for (int j = 0; j < 4; ++j) acc[i][j] = f32x4_zero();

#define PHASE(p)                                                                              \
  do {                                                                                        \
    constexpr int mh = (p) >> 1, nh = (p) & 1;                                                \
    bf16x8 af[MH][2], bfv[2][2];                                                              \
    _Pragma("unroll") for (int m = 0; m < MH; ++m) {                                          \
      const int rowA = wr * FM * 16 + mh * MH * 16 + m * 16 + fr;                             \
      const char* pa = lsA + buf * ABYTES + (rowA >> 7) * 16384 + (rowA & 127) * 128;         \
      const int sz = (rowA & 7) << 4;                                                         \
      af[m][0] = *(const bf16x8*)(pa + ((fq * 16) ^ sz));                                     \
      af[m][1] = *(const bf16x8*)(pa + ((64 + fq * 16) ^ sz));                                \
    }                                                                                         \
    _Pragma("unroll") for (int n = 0; n < 2; ++n) {                                           \
      const int rowB = wc * 64 + nh * 32 + n * 16 + fr;                                       \
      const char* pb = lsB + buf * BBYTES + (rowB >> 7) * 16384 + (rowB & 127) * 128;         \
      const int sz = (rowB & 7) << 4;                                                         \
      bfv[n][0] = *(const bf16x8*)(pb + ((fq * 16) ^ sz));                                    \
      bfv[n][1] = *(const bf16x8*)(pb + ((64 + fq * 16) ^ sz));                               \
    }                                                                                         \
    asm volatile("s_waitcnt lgkmcnt(0)" ::: "memory");                                        \
    __builtin_amdgcn_sched_barrier(0);                                                        \
    __builtin_amdgcn_s_setprio(1);                                                            \
    _Pragma("unroll") for (int m = 0; m < MH; ++m)                                            \
      _Pragma("unroll") for (int n = 0; n < 2; ++n) {                                         \
        acc[mh * MH + m][nh * 2 + n] =                                                        \
            __builtin_amdgcn_mfma_f32_16x16x32_bf16(af[m][0], bfv[n][0], acc[mh * MH + m][nh * 2 + n], 0, 0, 0); \
        acc[mh * MH + m][nh * 2 + n] =                                                        \
            __builtin_amdgcn_mfma_f32_16x16x32_bf16(af[m][1], bfv[n][1], acc[mh * MH + m][nh * 2 + n], 0, 0, 0); \
      }                                                                                       \
    __builtin_amdgcn_s_setprio(0);                                                            \
  } while (0)

  const int NT = K >> 6;

  // prologue: stage tile 0 into buf 0, full drain
  STAGE_A(0, 0, 0);
  if constexpr (FM == 8) STAGE_A(0, 0, 1);
  STAGE_B(0, 0, 0);
  STAGE_B(0, 0, 1);
  asm volatile("s_waitcnt vmcnt(0)" ::: "memory");
  __builtin_amdgcn_s_barrier();

  int buf = 0;
  for (int t = 0; t < NT; ++t) {
    const bool hn = (t + 1) < NT;
    // phase 0: stage + counted drain of tile t's fills + barrier
    if (hn) {
      STAGE_A(buf ^ 1, t + 1, 0);
      asm volatile("s_waitcnt vmcnt(2)" ::: "memory");
    } else {
      asm volatile("s_waitcnt vmcnt(0)" ::: "memory");
    }
    __builtin_amdgcn_s_barrier();
    PHASE(0);
    __builtin_amdgcn_s_barrier();
    // phase 1
    if (hn) {
      if constexpr (FM == 8) STAGE_A(buf ^ 1, t + 1, 1);
      else                   STAGE_B(buf ^ 1, t + 1, 0);
    }
    PHASE(1);
    __builtin_amdgcn_s_barrier();
    // phase 2
    if (hn) {
      if constexpr (FM == 8) STAGE_B(buf ^ 1, t + 1, 0);
      else                   STAGE_B(buf ^ 1, t + 1, 1);
    }
    PHASE(2);
    __builtin_amdgcn_s_barrier();
    // phase 3
    if (hn) {
      if constexpr (FM == 8) STAGE_B(buf ^ 1, t + 1, 1);
    }
    PHASE(3);
    __builtin_amdgcn_s_barrier();
    buf ^= 1;
  }

  // epilogue
#pragma unroll
  for (int i = 0; i < FM; ++i) {
    const int row = m0 + wr * FM * 16 + i * 16 + fq * 4;
#pragma unroll
    for (int j = 0; j < 4; ++j) {
      const int col = n0 + wc * 64 + j * 16 + fr;
#pragma unroll
      for (int v = 0; v < 4; ++v) {
        if (OUT_BF16) ((unsigned short*)Cv)[(size_t)(row + v) * N + col] = f2bf(acc[i][j][v]);
        else          ((float*)Cv)[(size_t)(row + v) * N + col] = acc[i][j][v];
      }
    }
  }
#undef STAGE_A
#undef STAGE_B
#undef PHASE
}

// ---------------------------------------------------------------- RoPE in-place on qkv
__global__ void rope_kernel(unsigned short* __restrict__ qkv,
                            const float* __restrict__ costab,
                            const float* __restrict__ sintab) {
  int idx = blockIdx.x * blockDim.x + threadIdx.x;
  if (idx >= 4096 * 1280) return;
  int row = idx / 1280;
  int p = idx - row * 1280;
  int s = row & 2047;
  int col, d; bool isq;
  if (p < 1024) { isq = true;  d = p & 31; col = (p >> 5) * 64 + d; }
  else { isq = false; int pk = p - 1024; d = pk & 31; col = 2048 + (pk >> 5) * 64 + d; }
  float c = costab[s * 32 + d], sn = sintab[s * 32 + d];
  unsigned short* base = qkv + (size_t)row * 3072;
  float x1 = bf2f(base[col]), x2 = bf2f(base[col + 32]);
  float o1 = x1 * c - x2 * sn;
  float o2 = x1 * sn + x2 * c;
  if (isq) { o1 *= 0.18033688011112042f; o2 *= 0.18033688011112042f; }  // 0.125*log2(e)
  base[col] = f2bf(o1);
  base[col + 32] = f2bf(o2);
}

// ---------------------------------------------------------------- flash attention (8-wave, dbuf)
__global__ __launch_bounds__(512, 4) void flash_attn(const unsigned short* __restrict__ qkv,
                                                     unsigned short* __restrict__ out) {
  __shared__ __align__(16) char K_sh[2 * 8192];
  __shared__ __align__(16) char V_sh[2 * 8192];
  __shared__ __align__(16) char P_sh[8 * 4096];

  const int tid = threadIdx.x;
  const int wave = tid >> 6, lane = tid & 63;
  const int fq = lane >> 4, fr = lane & 15;
  const int b = blockIdx.z, h = blockIdx.y;
  const int qt = gridDim.x - 1 - blockIdx.x;       // long blocks first
  const int kvh = h >> 2;
  const int q0 = qt * 256;
  const int wq0 = q0 + wave * 32;
  char* Pw = P_sh + wave * 4096;

  bf16x8 qreg[2][2];
#pragma unroll
  for (int qf = 0; qf < 2; ++qf)
#pragma unroll
    for (int kk = 0; kk < 2; ++kk)
      qreg[qf][kk] = *(const bf16x8*)(qkv + (size_t)(b * 2048 + wq0 + qf * 16 + fr) * 3072
                                      + h * 64 + kk * 32 + fq * 8);

  f32x4 o_acc[4][2];
  float m_run[2], l_run[2];
#pragma unroll
  for (int dc = 0; dc < 4; ++dc) { o_acc[dc][0] = f32x4_zero(); o_acc[dc][1] = f32x4_zero(); }
  m_run[0] = m_run[1] = -1e30f;
  l_run[0] = l_run[1] = 0.f;

  const char* kgbase = (const char*)qkv + (size_t)(b * 2048) * 6144 + 4096 + kvh * 128;
  const unsigned short* vgbase = qkv + (size_t)(b * 2048) * 3072 + 2560 + kvh * 64;
  const int nsteps = (q0 + 256) >> 6;

  const int vk2 = (tid >> 3) << 1;
  const int vc0 = (tid & 7) << 3;
  const int kt = tid - 256;

  {
    if (wave < 4) {
      bf16x8 vv0 = *(const bf16x8*)(vgbase + (size_t)vk2 * 3072 + vc0);
      bf16x8 vv1 = *(const bf16x8*)(vgbase + (size_t)(vk2 + 1) * 3072 + vc0);
#pragma unroll
      for (int j = 0; j < 8; ++j) {
        const int d = vc0 + j;
        const int G = ((d & 7) ^ (d >> 3)) & 7;
        unsigned int w = ((unsigned int)(unsigned short)vv0[j]) |
                         (((unsigned int)(unsigned short)vv1[j]) << 16);
        *(unsigned int*)(V_sh + (d << 7) + ((vk2 << 1) ^ (G << 4))) = w;
      }
    } else {
#pragma unroll
      for (int ld = 0; ld < 2; ++ld) {
        const int row = (kt >> 3) + (ld << 5);
        const int cb = ((kt & 7) << 4) ^ ((row & 7) << 4);
        __builtin_amdgcn_global_load_lds(GPTR(kgbase + (size_t)row * 6144 + cb),
                                         LPTR(K_sh + kt * 16 + ld * 4096), 16, 0, 0);
      }
    }
  }
  __syncthreads();

  int buf = 0;
  for (int st = 0; st < nsteps; ++st) {
    const int k0 = st << 6;
    const bool has_next = (st + 1) < nsteps;
    bf16x8 vv0, vv1;
    if (has_next) {
      const int k0n = k0 + 64;
      if (wave < 4) {
        vv0 = *(const bf16x8*)(vgbase + (size_t)(k0n + vk2) * 3072 + vc0);
        vv1 = *(const bf16x8*)(vgbase + (size_t)(k0n + vk2 + 1) * 3072 + vc0);
      } else {
        char* Kn = K_sh + (buf ^ 1) * 8192;
#pragma unroll
        for (int ld = 0; ld < 2; ++ld) {
          const int row = (kt >> 3) + (ld << 5);
          const int cb = ((kt & 7) << 4) ^ ((row & 7) << 4);
          __builtin_amdgcn_global_load_lds(GPTR(kgbase + (size_t)(k0n + row) * 6144 + cb),
                                           LPTR(Kn + kt * 16 + ld * 4096), 16, 0, 0);
        }
      }
    }

    if (k0 <= wq0 + 31) {
      const char* Kb = K_sh + buf * 8192;
      const char* Vb = V_sh + buf * 8192;
      f32x4 s[2][4];
#pragma unroll
      for (int qf = 0; qf < 2; ++qf)
#pragma unroll
        for (int kf = 0; kf < 4; ++kf) s[qf][kf] = f32x4_zero();
#pragma unroll
      for (int kf = 0; kf < 4; ++kf) {
        const int krow = kf * 16 + fr;
        const int swz = (krow & 7) << 4;
        bf16x8 ka = *(const bf16x8*)(Kb + krow * 128 + ((fq * 16) ^ swz));
        bf16x8 kb = *(const bf16x8*)(Kb + krow * 128 + ((64 + fq * 16) ^ swz));
#pragma unroll
        for (int qf = 0; qf < 2; ++qf) {
          s[qf][kf] = __builtin_amdgcn_mfma_f32_16x16x32_bf16(ka, qreg[qf][0], s[qf][kf], 0, 0, 0);
          s[qf][kf] = __builtin_amdgcn_mfma_f32_16x16x32_bf16(kb, qreg[qf][1], s[qf][kf], 0, 0, 0);
        }
      }
      if (k0 + 63 > wq0) {
#pragma unroll
        for (int qf = 0; qf < 2; ++qf) {
          const int q = wq0 + qf * 16 + fr;
#pragma unroll
          for (int kf = 0; kf < 4; ++kf)
#pragma unroll
            for (int v = 0; v < 4; ++v) {
              const int key = k0 + kf * 16 + fq * 4 + v;
              if (key > q) s[qf][kf][v] = -1e30f;
            }
        }
      }
#pragma unroll
      for (int qf = 0; qf < 2; ++qf) {
        float t = s[qf][0][0];
#pragma unroll
        for (int kf = 0; kf < 4; ++kf)
#pragma unroll
          for (int v = 0; v < 4; ++v) t = fmaxf(t, s[qf][kf][v]);
        t = fmaxf(t, __shfl_xor(t, 16));
        t = fmaxf(t, __shfl_xor(t, 32));
        const float mo = m_run[qf];
        const float mn = fmaxf(mo, t);
        const float sc = __builtin_amdgcn_exp2f(mo - mn);
        m_run[qf] = mn;
        float ps = 0.f;
#pragma unroll
        for (int kf = 0; kf < 4; ++kf)
#pragma unroll
          for (int v = 0; v < 4; ++v) {
            const float p = __builtin_amdgcn_exp2f(s[qf][kf][v] - mn);
            s[qf][kf][v] = p;
            ps += p;
          }
        ps += __shfl_xor(ps, 16);
        ps += __shfl_xor(ps, 32);
        l_run[qf] = l_run[qf] * sc + ps;
#pragma unroll
        for (int dc = 0; dc < 4; ++dc) o_acc[dc][qf] *= sc;
        const int r = qf * 16 + fr;
        const int rswz = (r & 7) << 4;
#pragma unroll
        for (int kf = 0; kf < 4; ++kf) {
          uint2 w;
          w.x = cvt_pk_bf16(s[qf][kf][0], s[qf][kf][1]);
          w.y = cvt_pk_bf16(s[qf][kf][2], s[qf][kf][3]);
          *(uint2*)(Pw + r * 128 + ((kf * 32 + fq * 8) ^ rswz)) = w;
        }
      }
      asm volatile("s_waitcnt lgkmcnt(0)" ::: "memory");
      __builtin_amdgcn_sched_barrier(0);
      const int fswz = (fr & 7) << 4;
#pragma unroll
      for (int kk = 0; kk < 2; ++kk) {
        bf16x8 pa0 = *(const bf16x8*)(Pw + fr * 128 + ((kk * 64 + fq * 16) ^ fswz));
        bf16x8 pa1 = *(const bf16x8*)(Pw + (16 + fr) * 128 + ((kk * 64 + fq * 16) ^ fswz));
#pragma unroll
        for (int dc = 0; dc < 4; ++dc) {
          const int d = dc * 16 + fr;
          const int G = ((d & 7) ^ (d >> 3)) & 7;
          bf16x8 vt = *(const bf16x8*)(Vb + d * 128 + ((kk * 64 + fq * 16) ^ (G << 4)));
          o_acc[dc][0] = __builtin_amdgcn_mfma_f32_16x16x32_bf16(vt, pa0, o_acc[dc][0], 0, 0, 0);
          o_acc[dc][1] = __builtin_amdgcn_mfma_f32_16x16x32_bf16(vt, pa1, o_acc[dc][1], 0, 0, 0);
        }
      }
    }

    if (has_next && wave < 4) {
      char* Vn = V_sh + (buf ^ 1) * 8192;
#pragma unroll
      for (int j = 0; j < 8; ++j) {
        const int d = vc0 + j;
        const int G = ((d & 7) ^ (d >> 3)) & 7;
        unsigned int w = ((unsigned int)(unsigned short)vv0[j]) |
                         (((unsigned int)(unsigned short)vv1[j]) << 16);
        *(unsigned int*)(Vn + (d << 7) + ((vk2 << 1) ^ (G << 4))) = w;
      }
    }
    __syncthreads();
    buf ^= 1;
  }

#pragma unroll
  for (int qf = 0; qf < 2; ++qf) {
    const float inv = 1.0f / l_run[qf];
    const size_t row = (size_t)(b * 2048 + wq0 + qf * 16 + fr);
#pragma unroll
    for (int dc = 0; dc < 4; ++dc) {
      u16x4 o;
#pragma unroll
      for (int v = 0; v < 4; ++v) o[v] = f2bf(o_acc[dc][qf][v] * inv);
      *(u16x4*)(out + row * 2048 + h * 64 + dc * 16 + fq * 4) = o;
    }
  }
}

// ---------------------------------------------------------------- launch
extern "C" void kernel_launch(void* const* d_in, const int* in_sizes, int n_in,
                              void* d_out, int out_size, void* d_ws, size_t ws_size,
                              hipStream_t stream) {
  (void)in_sizes; (void)n_in; (void)out_size; (void)ws_size;
  const float* x  = (const float*)d_in[0];
  const float* wq = (const float*)d_in[1];
  const float* wk = (const float*)d_in[2];
  const float* wv = (const float*)d_in[3];
  const float* wo = (const float*)d_in[4];

  char* wsb = (char*)d_ws;
  unsigned short* xb     = (unsigned short*)(wsb);
  unsigned short* attn_o = xb;
  unsigned short* wqkvb  = (unsigned short*)(wsb + 16777216);
  unsigned short* wob    = (unsigned short*)(wsb + 29360128);
  unsigned short* qkv    = (unsigned short*)(wsb + 37748736);
  float* costab          = (float*)(wsb + 62914560);
  float* sintab          = (float*)(wsb + 63176704);

  rope_table_kernel<<<256, 256, 0, stream>>>(costab, sintab);

  f32_to_bf16<<<2048, 256, 0, stream>>>(x,  xb,                 8388608 / 4);
  f32_to_bf16<<<1024, 256, 0, stream>>>(wq, wqkvb,              4194304 / 4);
  f32_to_bf16<<<256,  256, 0, stream>>>(wk, wqkvb + 4194304,    1048576 / 4);
  f32_to_bf16<<<256,  256, 0, stream>>>(wv, wqkvb + 5242880,    1048576 / 4);
  f32_to_bf16<<<1024, 256, 0, stream>>>(wo, wob,                4194304 / 4);

  // qkv = x @ [wq;wk;wv]^T : M=4096, N=3072, K=2048 ; 192 blocks (16x12)
  gemm8p<8, 1><<<192, 512, 0, stream>>>(xb, wqkvb, (void*)qkv, 4096, 3072, 2048, 12);

  rope_kernel<<<20480, 256, 0, stream>>>(qkv, costab, sintab);

  flash_attn<<<dim3(8, 32, 2), 512, 0, stream>>>(qkv, attn_o);

  // out = attn @ wo^T : M=4096, N=2048, K=2048 ; 256 blocks (32x8)
  gemm8p<4, 0><<<256, 512, 0, stream>>>(attn_o, wob, d_out, 4096, 2048, 2048, 8);
}